// Round 3
// baseline (953.853 us; speedup 1.0000x reference)
//
#include <hip/hip_runtime.h>
#include <math.h>

constexpr int N = 20000, E = 160000, Bb = 1000;
constexpr int DIN = 7, HID = 64, HEADS = 4, CTXD = 3, EDIM = 5, NL = 4;
constexpr int HH = HEADS * HID; // 256

__device__ __forceinline__ float wredsum(float v) {
#pragma unroll
  for (int o = 32; o; o >>= 1) v += __shfl_xor(v, o, 64);
  return v;
}

__device__ __forceinline__ float wredmax(float v) {
#pragma unroll
  for (int o = 32; o; o >>= 1) v = fmaxf(v, __shfl_xor(v, o, 64));
  return v;
}

__global__ void k_ctx(const float* __restrict__ ctx, const float* __restrict__ ctx_W,
                      const float* __restrict__ ctx_b, const float* __restrict__ form_tab,
                      const float* __restrict__ align_tab, const int* __restrict__ form,
                      const int* __restrict__ alig, float* __restrict__ c_out) {
  int t = blockIdx.x * blockDim.x + threadIdx.x;
  if (t >= Bb * HID) return;
  int b = t >> 6, j = t & 63;
  float a = ctx_b[j];
#pragma unroll
  for (int k = 0; k < CTXD; ++k) a += ctx[b * CTXD + k] * ctx_W[k * HID + j];
  a = fmaxf(a, 0.f);
  a += form_tab[form[b] * HID + j] + align_tab[alig[b] * HID + j];
  c_out[t] = a;
}

__global__ void k_node_init(const float* __restrict__ x, const float* __restrict__ emb_W,
                            const float* __restrict__ emb_b, const int* __restrict__ role,
                            const float* __restrict__ role_tab, const int* __restrict__ side,
                            const float* __restrict__ side_tab, const float* __restrict__ frame_t,
                            const float* __restrict__ temp_tab, const int* __restrict__ batch,
                            const float* __restrict__ c_ctx, float* __restrict__ h) {
  int t = blockIdx.x * blockDim.x + threadIdx.x;
  if (t >= N * HID) return;
  int n = t >> 6, j = t & 63;
  float a = emb_b[j];
#pragma unroll
  for (int k = 0; k < DIN; ++k) a += x[n * DIN + k] * emb_W[k * HID + j];
  a = fmaxf(a, 0.f);
  a += role_tab[role[n] * HID + j];
  if (j < 32) a += side_tab[side[n] * 32 + j];
  int ti = (int)(frame_t[0] * 99.f);
  ti = ti < 0 ? 0 : (ti > 99 ? 99 : ti);
  a += temp_tab[ti * HID + j];
  a += c_ctx[batch[n] * HID + j];
  h[t] = a;
}

__global__ void k_count(const int* __restrict__ ei, int* __restrict__ deg_dst,
                        int* __restrict__ deg_src) {
  int e = blockIdx.x * blockDim.x + threadIdx.x;
  if (e >= E) return;
  atomicAdd(&deg_src[ei[e]], 1);
  atomicAdd(&deg_dst[ei[E + e]], 1);
}

// both exclusive scans in one launch; shfl wave-scan + cross-wave LDS
__global__ void k_scan2(const int* __restrict__ degA, int* __restrict__ rowA,
                        int* __restrict__ curA, const int* __restrict__ degB,
                        int* __restrict__ rowB, int* __restrict__ curB, int n) {
  __shared__ int wsum[16];
  __shared__ int carry;
  int t = threadIdx.x, wid = t >> 6, lane = t & 63;
  for (int pass = 0; pass < 2; ++pass) {
    const int* deg = pass ? degB : degA;
    int* row = pass ? rowB : rowA;
    int* cur = pass ? curB : curA;
    if (t == 0) carry = 0;
    __syncthreads();
    for (int base = 0; base < n; base += 1024) {
      int v = (base + t < n) ? deg[base + t] : 0;
      int s = v;
#pragma unroll
      for (int off = 1; off < 64; off <<= 1) {
        int x = __shfl_up(s, off, 64);
        if (lane >= off) s += x;
      }
      if (lane == 63) wsum[wid] = s;
      __syncthreads();
      if (wid == 0) {
        int ws = (lane < 16) ? wsum[lane] : 0;
#pragma unroll
        for (int off = 1; off < 16; off <<= 1) {
          int x = __shfl_up(ws, off, 64);
          if (lane >= off) ws += x;
        }
        if (lane < 16) wsum[lane] = ws;
      }
      __syncthreads();
      int wexcl = (wid == 0) ? 0 : wsum[wid - 1];
      int r = carry + wexcl + (s - v);
      if (base + t < n) {
        row[base + t] = r;
        cur[base + t] = r;
      }
      __syncthreads();
      if (t == 0) carry += wsum[15];
      __syncthreads();
    }
  }
}

// emits: dst-sorted (eid_dst, esrc_dst) and src-sorted (esrc_srt, edst_srt)
__global__ void k_scatter(const int* __restrict__ ei, int* __restrict__ cur_dst,
                          int* __restrict__ cur_src, int* __restrict__ eid_dst,
                          int* __restrict__ esrc_dst, int* __restrict__ esrc_srt,
                          int* __restrict__ edst_srt) {
  int e = blockIdx.x * blockDim.x + threadIdx.x;
  if (e >= E) return;
  int s = ei[e], d = ei[E + e];
  int ps = atomicAdd(&cur_src[s], 1);
  esrc_srt[ps] = s;
  edst_srt[ps] = d;
  int pd = atomicAdd(&cur_dst[d], 1);
  eid_dst[pd] = e;
  esrc_dst[pd] = s;
}

__global__ void k_loop_attr(const int* __restrict__ row_dst, const int* __restrict__ deg_dst,
                            const int* __restrict__ eid_dst, const float* __restrict__ ea,
                            float* __restrict__ la) {
  int n = blockIdx.x * blockDim.x + threadIdx.x;
  if (n >= N) return;
  int beg = row_dst[n], cnt = deg_dst[n];
  float s[EDIM] = {0.f, 0.f, 0.f, 0.f, 0.f};
  for (int j = 0; j < cnt; ++j) {
    int e = eid_dst[beg + j];
#pragma unroll
    for (int k = 0; k < EDIM; ++k) s[k] += ea[(size_t)e * EDIM + k];
  }
  float inv = 1.f / fmaxf((float)cnt, 1.f);
#pragma unroll
  for (int k = 0; k < EDIM; ++k) la[n * EDIM + k] = s[k] * inv;
}

__global__ __launch_bounds__(256) void k_xlxr(const float* __restrict__ h,
                                              const float* __restrict__ Wl,
                                              const float* __restrict__ bl,
                                              const float* __restrict__ Wr,
                                              const float* __restrict__ br,
                                              float* __restrict__ xl, float* __restrict__ xr) {
  constexpr int NB = 16;
  __shared__ float hs[NB][HID];
  int n0 = blockIdx.x * NB;
  for (int idx = threadIdx.x; idx < NB * HID; idx += 256) {
    int r = idx >> 6, c = idx & 63;
    int n = n0 + r;
    hs[r][c] = (n < N) ? h[n * HID + c] : 0.f;
  }
  __syncthreads();
  int t = threadIdx.x;
  float wl[HID], wr[HID];
#pragma unroll
  for (int k = 0; k < HID; ++k) {
    wl[k] = Wl[k * HH + t];
    wr[k] = Wr[k * HH + t];
  }
  float blv = bl[t], brv = br[t];
  for (int r = 0; r < NB; ++r) {
    int n = n0 + r;
    if (n >= N) break;
    float al = blv, ar = brv;
#pragma unroll
    for (int k = 0; k < HID; ++k) {
      float hv = hs[r][k];
      al += hv * wl[k];
      ar += hv * wr[k];
    }
    xl[(size_t)n * HH + t] = al;
    xr[(size_t)n * HH + t] = ar;
  }
}

// per-node GATv2, phase-split: (1) independent logit loop (lane-cached edge ids),
// (2) wave-parallel max/exp/sum, (3) pure-FMA accumulate with re-gather.
__global__ __launch_bounds__(256) void k_gat(
    const float* __restrict__ xl, const float* __restrict__ xr, const float* __restrict__ ea,
    const float* __restrict__ la, const int* __restrict__ row_dst,
    const int* __restrict__ deg_dst, const int* __restrict__ eid_dst,
    const int* __restrict__ esrc_dst, const float* __restrict__ We,
    const float* __restrict__ att, const float* __restrict__ biasL,
    const float* __restrict__ lng, const float* __restrict__ lnb, float* __restrict__ h) {
  int n = blockIdx.x;
  int w = threadIdx.x >> 6, lane = threadIdx.x & 63;
  int col = w * HID + lane;
  float xr_d = xr[(size_t)n * HH + col];
  float attw = att[col];
  float we[EDIM];
#pragma unroll
  for (int k = 0; k < EDIM; ++k) we[k] = We[k * HH + col];
  int beg = row_dst[n], cnt = deg_dst[n];
  int tot = cnt + 1;  // + self loop (idx 0)
  int ncache = cnt < 63 ? cnt : 63;
  int srcn_c = (lane < ncache) ? esrc_dst[beg + lane] : 0;
  int eid_c = (lane < ncache) ? eid_dst[beg + lane] : 0;
  int nf = tot < 64 ? tot : 64;
  float mylg = -INFINITY;
  for (int idx = 0; idx < nf; ++idx) {
    int srcn = (idx == 0) ? n : __shfl(srcn_c, idx - 1, 64);
    const float* eap;
    if (idx == 0) {
      eap = la + (size_t)n * EDIM;
    } else {
      int e = __shfl(eid_c, idx - 1, 64);
      eap = ea + (size_t)e * EDIM;
    }
    float ep = 0.f;
#pragma unroll
    for (int k = 0; k < EDIM; ++k) ep += eap[k] * we[k];
    float xls = xl[(size_t)srcn * HH + col];
    float v = xls + xr_d + ep;
    v = v > 0.f ? v : 0.2f * v;
    float lg = wredsum(v * attw);
    if (lane == idx) mylg = lg;
  }
  float m = wredmax(mylg);  // lanes >= nf hold -INF
  float p = (lane < nf) ? __expf(mylg - m) : 0.f;
  float s = wredsum(p);
  float acc = 0.f;
  for (int idx = 0; idx < nf; ++idx) {
    int srcn = (idx == 0) ? n : __shfl(srcn_c, idx - 1, 64);
    float pi = __shfl(p, idx, 64);
    acc += pi * xl[(size_t)srcn * HH + col];
  }
  // overflow (deg > 63), rare: online merge
  for (int idx = nf; idx < tot; ++idx) {
    int pos = beg + idx - 1;
    int srcn = esrc_dst[pos];
    int e = eid_dst[pos];
    const float* eap = ea + (size_t)e * EDIM;
    float ep = 0.f;
#pragma unroll
    for (int k = 0; k < EDIM; ++k) ep += eap[k] * we[k];
    float xls = xl[(size_t)srcn * HH + col];
    float v = xls + xr_d + ep;
    v = v > 0.f ? v : 0.2f * v;
    float lg = wredsum(v * attw);
    float nm = fmaxf(m, lg);
    float sc = __expf(m - nm), pp = __expf(lg - nm);
    s = s * sc + pp;
    acc = acc * sc + pp * xls;
    m = nm;
  }
  float outv = acc / (s + 1e-16f);
  __shared__ float heads[HEADS][HID];
  heads[w][lane] = outv;
  __syncthreads();
  if (w == 0) {
    float hv = (heads[0][lane] + heads[1][lane] + heads[2][lane] + heads[3][lane]) * 0.25f +
               biasL[lane];
    hv = fmaxf(hv, 0.f);
    float v = hv + h[n * HID + lane];
    float mu = wredsum(v) * (1.f / 64.f);
    float d = v - mu;
    float var = wredsum(d * d) * (1.f / 64.f);
    h[n * HID + lane] = d * rsqrtf(var + 1e-5f) * lng[lane] + lnb[lane];
  }
}

__global__ __launch_bounds__(256) void k_uv(const float* __restrict__ h,
                                            const float* __restrict__ W1,
                                            const float* __restrict__ b1,
                                            float* __restrict__ u, float* __restrict__ v) {
  constexpr int NB = 16;
  __shared__ float hs[NB][HID];
  int n0 = blockIdx.x * NB;
  for (int idx = threadIdx.x; idx < NB * HID; idx += 256) {
    int r = idx >> 6, c = idx & 63;
    int n = n0 + r;
    hs[r][c] = (n < N) ? h[n * HID + c] : 0.f;
  }
  __syncthreads();
  int j = threadIdx.x & 63, q = threadIdx.x >> 6;
  float wa[HID], wb[HID];
#pragma unroll
  for (int k = 0; k < HID; ++k) {
    wa[k] = W1[k * HID + j];
    wb[k] = W1[(HID + k) * HID + j];
  }
  float b1v = b1[j];
  for (int r = q; r < NB; r += 4) {
    int n = n0 + r;
    if (n >= N) continue;
    float au = b1v, av = 0.f;
#pragma unroll
    for (int k = 0; k < HID; ++k) {
      float hv = hs[r][k];
      au += hv * wa[k];
      av += hv * wb[k];
    }
    u[(size_t)n * HID + j] = au;
    v[(size_t)n * HID + j] = av;
  }
}

// wave-per-64-edges; LDS transpose tile for coalesced gather AND store
__global__ __launch_bounds__(64) void k_edge(const float* __restrict__ u,
                                             const float* __restrict__ v,
                                             const int* __restrict__ esrc_srt,
                                             const int* __restrict__ edst_srt,
                                             const float* __restrict__ W2,
                                             const float* __restrict__ b2,
                                             const float* __restrict__ Wg,
                                             const float* __restrict__ bg,
                                             float* __restrict__ gated) {
  __shared__ float tile[64 * 65];
  int lane = threadIdx.x;
  int p0 = blockIdx.x * 64;  // E % 64 == 0
  int s = esrc_srt[p0 + lane];
  int d = edst_srt[p0 + lane];
  // phase A: coalesced row gathers, transposed into LDS
  for (int i = 0; i < 64; ++i) {
    int si = __shfl(s, i, 64), di = __shfl(d, i, 64);
    float pv = u[(size_t)si * HID + lane] + v[(size_t)di * HID + lane];
    tile[i * 65 + lane] = fmaxf(pv, 0.f);
  }
  // phase B: per-thread register GEMVs (thread = edge)
  float pre[HID];
#pragma unroll
  for (int k = 0; k < HID; ++k) pre[k] = tile[lane * 65 + k];
  float it[HID];
#pragma unroll
  for (int jb = 0; jb < 8; ++jb) {
    float a0 = b2[jb * 8 + 0], a1 = b2[jb * 8 + 1], a2 = b2[jb * 8 + 2], a3 = b2[jb * 8 + 3];
    float a4 = b2[jb * 8 + 4], a5 = b2[jb * 8 + 5], a6 = b2[jb * 8 + 6], a7 = b2[jb * 8 + 7];
#pragma unroll
    for (int k = 0; k < HID; ++k) {
      const float* wr = W2 + k * HID + jb * 8;
      float pk = pre[k];
      a0 += pk * wr[0]; a1 += pk * wr[1]; a2 += pk * wr[2]; a3 += pk * wr[3];
      a4 += pk * wr[4]; a5 += pk * wr[5]; a6 += pk * wr[6]; a7 += pk * wr[7];
    }
    it[jb * 8 + 0] = a0; it[jb * 8 + 1] = a1; it[jb * 8 + 2] = a2; it[jb * 8 + 3] = a3;
    it[jb * 8 + 4] = a4; it[jb * 8 + 5] = a5; it[jb * 8 + 6] = a6; it[jb * 8 + 7] = a7;
  }
#pragma unroll
  for (int jb = 0; jb < 8; ++jb) {
    float g0 = bg[jb * 8 + 0], g1 = bg[jb * 8 + 1], g2 = bg[jb * 8 + 2], g3 = bg[jb * 8 + 3];
    float g4 = bg[jb * 8 + 4], g5 = bg[jb * 8 + 5], g6 = bg[jb * 8 + 6], g7 = bg[jb * 8 + 7];
#pragma unroll
    for (int k = 0; k < HID; ++k) {
      const float* wr = Wg + k * HID + jb * 8;
      float ik = it[k];
      g0 += ik * wr[0]; g1 += ik * wr[1]; g2 += ik * wr[2]; g3 += ik * wr[3];
      g4 += ik * wr[4]; g5 += ik * wr[5]; g6 += ik * wr[6]; g7 += ik * wr[7];
    }
    tile[lane * 65 + jb * 8 + 0] = it[jb * 8 + 0] / (1.f + __expf(-g0));
    tile[lane * 65 + jb * 8 + 1] = it[jb * 8 + 1] / (1.f + __expf(-g1));
    tile[lane * 65 + jb * 8 + 2] = it[jb * 8 + 2] / (1.f + __expf(-g2));
    tile[lane * 65 + jb * 8 + 3] = it[jb * 8 + 3] / (1.f + __expf(-g3));
    tile[lane * 65 + jb * 8 + 4] = it[jb * 8 + 4] / (1.f + __expf(-g4));
    tile[lane * 65 + jb * 8 + 5] = it[jb * 8 + 5] / (1.f + __expf(-g5));
    tile[lane * 65 + jb * 8 + 6] = it[jb * 8 + 6] / (1.f + __expf(-g6));
    tile[lane * 65 + jb * 8 + 7] = it[jb * 8 + 7] / (1.f + __expf(-g7));
  }
  // phase C: coalesced contiguous store (16 KB per wave)
  for (int i = 0; i < 64; ++i) {
    gated[(size_t)(p0 + i) * HID + lane] = tile[i * 65 + lane];
  }
}

__global__ void k_pool(const float* __restrict__ h, const float* __restrict__ gated,
                       const int* __restrict__ row_src, const int* __restrict__ deg_src,
                       const float* __restrict__ g, const float* __restrict__ b,
                       float* __restrict__ out) {
  int n = blockIdx.x * 4 + (threadIdx.x >> 6);
  int lane = threadIdx.x & 63;
  if (n >= N) return;
  int beg = row_src[n], cnt = deg_src[n];
  float acc = 0.f;
  for (int i = 0; i < cnt; ++i) acc += gated[(size_t)(beg + i) * HID + lane];
  float v = h[n * HID + lane] + acc / fmaxf((float)cnt, 1.f);
  float mu = wredsum(v) * (1.f / 64.f);
  float d = v - mu;
  float var = wredsum(d * d) * (1.f / 64.f);
  out[n * HID + lane] = d * rsqrtf(var + 1e-5f) * g[lane] + b[lane];
}

extern "C" void kernel_launch(void* const* d_in, const int* in_sizes, int n_in, void* d_out,
                              int out_size, void* d_ws, size_t ws_size, hipStream_t stream) {
  const float* x = (const float*)d_in[0];
  const int* ei = (const int*)d_in[1];
  const float* eattr = (const float*)d_in[2];
  const float* ctx = (const float*)d_in[3];
  const int* batch = (const int*)d_in[4];
  const int* role = (const int*)d_in[5];
  const int* side = (const int*)d_in[6];
  const int* form = (const int*)d_in[7];
  const int* alig = (const int*)d_in[8];
  const float* frame_t = (const float*)d_in[9];
  const float* emb_W = (const float*)d_in[10];
  const float* emb_b = (const float*)d_in[11];
  const float* role_tab = (const float*)d_in[12];
  const float* side_tab = (const float*)d_in[13];
  const float* ctx_W = (const float*)d_in[14];
  const float* ctx_b = (const float*)d_in[15];
  const float* form_tab = (const float*)d_in[16];
  const float* align_tab = (const float*)d_in[17];
  const float* temp_tab = (const float*)d_in[18];
  const float* gat_Wl = (const float*)d_in[19];
  const float* gat_bl = (const float*)d_in[20];
  const float* gat_Wr = (const float*)d_in[21];
  const float* gat_br = (const float*)d_in[22];
  const float* gat_We = (const float*)d_in[23];
  const float* gat_att = (const float*)d_in[24];
  const float* gat_bias = (const float*)d_in[25];
  const float* ln_g = (const float*)d_in[26];
  const float* ln_b = (const float*)d_in[27];
  const float* sp_W1 = (const float*)d_in[28];
  const float* sp_b1 = (const float*)d_in[29];
  const float* sp_W2 = (const float*)d_in[30];
  const float* sp_b2 = (const float*)d_in[31];
  const float* sp_Wg = (const float*)d_in[32];
  const float* sp_bg = (const float*)d_in[33];
  const float* fn_g = (const float*)d_in[34];
  const float* fn_b = (const float*)d_in[35];
  float* out = (float*)d_out;

  char* wp = (char*)d_ws;
  auto alloc = [&](size_t bytes) {
    void* p = (void*)wp;
    wp += (bytes + 255) & ~(size_t)255;
    return p;
  };
  float* c_ctx = (float*)alloc((size_t)Bb * HID * 4);
  float* h = (float*)alloc((size_t)N * HID * 4);
  float* xl = (float*)alloc((size_t)N * HH * 4);  // + xr below = 41 MB, reused as gated[E][64]
  float* xr = (float*)alloc((size_t)N * HH * 4);
  float* la = (float*)alloc((size_t)N * EDIM * 4);
  float* u = (float*)alloc((size_t)N * HID * 4);
  float* v = (float*)alloc((size_t)N * HID * 4);
  int* deg_dst = (int*)alloc((size_t)N * 4);
  int* deg_src = (int*)alloc((size_t)N * 4);
  int* row_dst = (int*)alloc((size_t)N * 4);
  int* row_src = (int*)alloc((size_t)N * 4);
  int* cur_dst = (int*)alloc((size_t)N * 4);
  int* cur_src = (int*)alloc((size_t)N * 4);
  int* eid_dst = (int*)alloc((size_t)E * 4);
  int* esrc_dst = (int*)alloc((size_t)E * 4);
  int* esrc_srt = (int*)alloc((size_t)E * 4);
  int* edst_srt = (int*)alloc((size_t)E * 4);
  float* gated = xl;  // [E][64] = 41 MB, spans xl+xr (both dead by then)

  hipMemsetAsync(deg_dst, 0, (size_t)N * 4, stream);
  hipMemsetAsync(deg_src, 0, (size_t)N * 4, stream);

  k_ctx<<<(Bb * HID + 255) / 256, 256, 0, stream>>>(ctx, ctx_W, ctx_b, form_tab, align_tab, form,
                                                    alig, c_ctx);
  k_node_init<<<(N * HID + 255) / 256, 256, 0, stream>>>(x, emb_W, emb_b, role, role_tab, side,
                                                         side_tab, frame_t, temp_tab, batch, c_ctx,
                                                         h);
  k_count<<<(E + 255) / 256, 256, 0, stream>>>(ei, deg_dst, deg_src);
  k_scan2<<<1, 1024, 0, stream>>>(deg_dst, row_dst, cur_dst, deg_src, row_src, cur_src, N);
  k_scatter<<<(E + 255) / 256, 256, 0, stream>>>(ei, cur_dst, cur_src, eid_dst, esrc_dst,
                                                 esrc_srt, edst_srt);
  k_loop_attr<<<(N + 255) / 256, 256, 0, stream>>>(row_dst, deg_dst, eid_dst, eattr, la);

  for (int i = 0; i < NL; ++i) {
    k_xlxr<<<(N + 15) / 16, 256, 0, stream>>>(h, gat_Wl + (size_t)i * HID * HH, gat_bl + i * HH,
                                              gat_Wr + (size_t)i * HID * HH, gat_br + i * HH, xl,
                                              xr);
    k_gat<<<N, 256, 0, stream>>>(xl, xr, eattr, la, row_dst, deg_dst, eid_dst, esrc_dst,
                                 gat_We + (size_t)i * EDIM * HH, gat_att + i * HH,
                                 gat_bias + i * HID, ln_g + i * HID, ln_b + i * HID, h);
  }

  k_uv<<<(N + 15) / 16, 256, 0, stream>>>(h, sp_W1, sp_b1, u, v);
  k_edge<<<E / 64, 64, 0, stream>>>(u, v, esrc_srt, edst_srt, sp_W2, sp_b2, sp_Wg, sp_bg, gated);
  k_pool<<<(N + 3) / 4, 256, 0, stream>>>(h, gated, row_src, deg_src, fn_g, fn_b, out);
}